// Round 10
// baseline (292.539 us; speedup 1.0000x reference)
//
#include <hip/hip_runtime.h>

#define NN 50000
#define NE 400000
#define NG 128
#define FIN 768
#define HIDF 256
#define OUTF 128
#define A1B 12500   // att1 blocks before rootcontrib tail

typedef __attribute__((ext_vector_type(4))) float f32x4;
typedef __attribute__((ext_vector_type(8))) short bf16x8;

__device__ __forceinline__ short f2bf(float f) {
  union { float f; unsigned u; } v; v.f = f;
  unsigned r = v.u + 0x7FFFu + ((v.u >> 16) & 1u);   // RNE
  return (short)(r >> 16);
}
__device__ __forceinline__ float lrelu(float x) { return x > 0.f ? x : 0.2f * x; }
__device__ __forceinline__ f32x4 b4f(ushort4 v) {
  union { unsigned u; float f; } t;
  f32x4 r;
  t.u = (unsigned)v.x << 16; r[0] = t.f;
  t.u = (unsigned)v.y << 16; r[1] = t.f;
  t.u = (unsigned)v.z << 16; r[2] = t.f;
  t.u = (unsigned)v.w << 16; r[3] = t.f;
  return r;
}
__device__ __forceinline__ float sel4(float4 v, int head) {
  float t0 = (head & 1) ? v.y : v.x;
  float t1 = (head & 1) ? v.w : v.z;
  return (head & 2) ? t1 : t0;
}

__device__ __forceinline__ void gload16(const short* g, short* l) {
  __builtin_amdgcn_global_load_lds(
      (const __attribute__((address_space(1))) unsigned int*)g,
      (__attribute__((address_space(3))) unsigned int*)l, 16, 0, 0);
}

// ---------------- zero deg + rootflag
__global__ __launch_bounds__(256) void zero_kernel(int* __restrict__ deg,
                                                   int* __restrict__ rootflag) {
  int i = blockIdx.x * 256 + threadIdx.x;
  if (i < NN) { deg[i] = 0; rootflag[i] = 0; }
}

// ---------------- fused prep: x->bf16, W1^T->bf16, W2[:256]^T->bf16, deg histogram
__global__ __launch_bounds__(256) void prep_kernel(
    const float* __restrict__ x, short* __restrict__ xb,
    const float* __restrict__ W1, short* __restrict__ W1T,
    const float* __restrict__ W2, short* __restrict__ W2T,
    const int* __restrict__ dstv, int* __restrict__ deg) {
  int b = blockIdx.x;
  if (b < 2048) {                       // convert x (4.8M groups of 8)
    long n8 = (long)NN * FIN / 8;
    for (long i = (long)b * 256 + threadIdx.x; i < n8; i += 2048 * 256) {
      f32x4 v0 = ((const f32x4*)x)[i * 2];
      f32x4 v1 = ((const f32x4*)x)[i * 2 + 1];
      bf16x8 o;
      o[0] = f2bf(v0[0]); o[1] = f2bf(v0[1]); o[2] = f2bf(v0[2]); o[3] = f2bf(v0[3]);
      o[4] = f2bf(v1[0]); o[5] = f2bf(v1[1]); o[6] = f2bf(v1[2]); o[7] = f2bf(v1[3]);
      ((bf16x8*)xb)[i] = o;
    }
  } else if (b < 2048 + 768) {          // W1T[c*768+k] = W1[k*256+c]
    int idx = (b - 2048) * 256 + threadIdx.x;
    int c = idx / FIN, k = idx - c * FIN;
    W1T[idx] = f2bf(W1[(long)k * HIDF + c]);
  } else if (b < 2048 + 768 + 128) {    // W2T[c*256+k] = W2[k*128+c], k<256
    int idx = (b - 2816) * 256 + threadIdx.x;
    int c = idx / HIDF, k = idx - c * HIDF;
    W2T[idx] = f2bf(W2[(long)k * OUTF + c]);
  } else {                              // deg histogram
    int e = (b - 2944) * 256 + threadIdx.x;
    if (e < NE) atomicAdd(&deg[dstv[e]], 1);
  }
}

// ---------------- MFMA GEMM, async global_load_lds staging, fused alphas, bf16 C
template<bool ADD_RC, int HEAD_SHIFT>
__global__ __launch_bounds__(256, 2) void gemm_kernel(
    const short* __restrict__ A, const short* __restrict__ Bt,
    short* __restrict__ C, int M, int K, int NC,
    const int* __restrict__ batch, const float* __restrict__ rc,
    const float* __restrict__ a_s, const float* __restrict__ a_d,
    float* __restrict__ as_out, float* __restrict__ ad_out)
{
  __shared__ short As[2][128 * 64];
  __shared__ short Bs[2][128 * 64];
  const int tid = threadIdx.x;
  const int l = tid & 63;
  const int w = tid >> 6;
  const int wm = w >> 1, wn = w & 1;
  const int bm = blockIdx.x, bn = blockIdx.y;
  const int nsteps = K >> 6;
  f32x4 acc[4][4] = {};

  auto issue = [&](int buf, int kt) {
    #pragma unroll
    for (int j = 0; j < 4; ++j) {
      int c = w * 4 + j;
      int q = c * 64 + l;
      int row = q >> 3, js = q & 7;
      int kg = js ^ (row & 7);            // source-address pre-swizzle
      long grow = (long)bm * 128 + row; if (grow >= M) grow = M - 1;
      gload16(A + grow * (long)K + kt * 64 + kg * 8, &As[buf][c * 512]);
    }
    #pragma unroll
    for (int j = 0; j < 4; ++j) {
      int c = w * 4 + j;
      int q = c * 64 + l;
      int row = q >> 3, js = q & 7;
      int kg = js ^ (row & 7);
      gload16(Bt + (long)(bn * 128 + row) * K + kt * 64 + kg * 8, &Bs[buf][c * 512]);
    }
  };

  issue(0, 0);
  if (nsteps > 1) {
    issue(1, 1);
    asm volatile("s_waitcnt vmcnt(8)" ::: "memory");
  } else {
    asm volatile("s_waitcnt vmcnt(0)" ::: "memory");
  }
  __builtin_amdgcn_s_barrier();

  for (int kt = 0; kt < nsteps; ++kt) {
    const int buf = kt & 1;
    const char* Ab = (const char*)&As[buf][0];
    const char* Bb = (const char*)&Bs[buf][0];
    #pragma unroll
    for (int ks = 0; ks < 2; ++ks) {
      bf16x8 af[4], bfr[4];
      #pragma unroll
      for (int mf = 0; mf < 4; ++mf) {
        int row = wm * 64 + mf * 16 + (l & 15);
        int off = (row * 128 + ks * 64 + (l >> 4) * 16) ^ ((row & 7) << 4);
        af[mf] = *(const bf16x8*)(Ab + off);
      }
      #pragma unroll
      for (int nf = 0; nf < 4; ++nf) {
        int row = wn * 64 + nf * 16 + (l & 15);
        int off = (row * 128 + ks * 64 + (l >> 4) * 16) ^ ((row & 7) << 4);
        bfr[nf] = *(const bf16x8*)(Bb + off);
      }
      #pragma unroll
      for (int mf = 0; mf < 4; ++mf)
        #pragma unroll
        for (int nf = 0; nf < 4; ++nf)
          acc[mf][nf] = __builtin_amdgcn_mfma_f32_16x16x32_bf16(af[mf], bfr[nf], acc[mf][nf], 0, 0, 0);
    }
    if (kt + 1 < nsteps) {
      asm volatile("s_waitcnt lgkmcnt(0)" ::: "memory");
      __builtin_amdgcn_s_barrier();
      if (kt + 2 < nsteps) {
        issue(buf, kt + 2);
        asm volatile("s_waitcnt vmcnt(8)" ::: "memory");
      } else {
        asm volatile("s_waitcnt vmcnt(0)" ::: "memory");
      }
      __builtin_amdgcn_s_barrier();
    }
  }

  // ---- epilogue: bf16 C store + fused per-head alpha dot products
  float asr[4], adr[4];
  #pragma unroll
  for (int nf = 0; nf < 4; ++nf) {
    int col = bn * 128 + wn * 64 + nf * 16 + (l & 15);
    asr[nf] = a_s[col]; adr[nf] = a_d[col];
  }
  #pragma unroll
  for (int mf = 0; mf < 4; ++mf) {
    #pragma unroll
    for (int r = 0; r < 4; ++r) {
      long grow = (long)bm * 128 + wm * 64 + mf * 16 + (l >> 4) * 4 + r;
      bool valid = grow < M;
      long rcb = 0;
      if (ADD_RC && valid) rcb = (long)batch[grow] * 128;
      float ps0 = 0, pd0 = 0, ps1 = 0, pd1 = 0;
      #pragma unroll
      for (int nf = 0; nf < 4; ++nf) {
        int col = bn * 128 + wn * 64 + nf * 16 + (l & 15);
        float v = acc[mf][nf][r];
        if (ADD_RC && valid) v += rc[rcb + col];
        if (valid) C[grow * (long)NC + col] = f2bf(v);
        float vs = v * asr[nf], vd = v * adr[nf];
        if (HEAD_SHIFT == 6 || nf < 2) { ps0 += vs; pd0 += vd; }
        else { ps1 += vs; pd1 += vd; }
      }
      #pragma unroll
      for (int off = 1; off < 16; off <<= 1) {
        ps0 += __shfl_xor(ps0, off); pd0 += __shfl_xor(pd0, off);
        if (HEAD_SHIFT == 5) { ps1 += __shfl_xor(ps1, off); pd1 += __shfl_xor(pd1, off); }
      }
      if (valid && (l & 15) == 0) {
        if (HEAD_SHIFT == 6) {
          int h0 = bn * 2 + wn;
          as_out[grow * 4 + h0] = ps0; ad_out[grow * 4 + h0] = pd0;
        } else {
          int h0 = wn * 2;
          as_out[grow * 4 + h0] = ps0;     ad_out[grow * 4 + h0] = pd0;
          as_out[grow * 4 + h0 + 1] = ps1; ad_out[grow * 4 + h0 + 1] = pd1;
        }
      }
    }
  }
}

// ---------------- CSR scan chain
__global__ void scan_block(const int* __restrict__ in, int* __restrict__ out,
                           int* __restrict__ bsum, int n) {
  __shared__ int sh[256];
  int i = blockIdx.x * 256 + threadIdx.x;
  int v = (i < n) ? in[i] : 0;
  int sum = v;
  sh[threadIdx.x] = v; __syncthreads();
  #pragma unroll
  for (int off = 1; off < 256; off <<= 1) {
    int t = (threadIdx.x >= off) ? sh[threadIdx.x - off] : 0;
    __syncthreads();
    sum += t;
    sh[threadIdx.x] = sum;
    __syncthreads();
  }
  if (i < n) out[i] = sum - v;     // exclusive
  if (threadIdx.x == 255) bsum[blockIdx.x] = sum;
}
__global__ void scan_add(int* __restrict__ offs, const int* __restrict__ bsumx,
                         int* __restrict__ cursor, int n, int total) {
  int i = blockIdx.x * 256 + threadIdx.x;
  if (i < n) { int v = offs[i] + bsumx[i >> 8]; offs[i] = v; cursor[i] = v; }
  if (i == n) offs[n] = total;
}
// scatter + graph-root pointers fused
__global__ void scatter_ptr_kernel(const int* __restrict__ src, const int* __restrict__ dst,
                                   int* __restrict__ cursor, int* __restrict__ csr,
                                   const int* __restrict__ batch, int* __restrict__ ptrv,
                                   int* __restrict__ rootflag) {
  if (blockIdx.x < 1563) {
    int e = blockIdx.x * 256 + threadIdx.x;
    if (e < NE) { int d = dst[e]; int p = atomicAdd(&cursor[d], 1); csr[p] = src[e]; }
    return;
  }
  int g = threadIdx.x;
  if (g <= NG) {
    if (g == NG) ptrv[NG] = NN;
    else {
      int lo = 0, hi = NN;
      while (lo < hi) { int mid = (lo + hi) >> 1; if (batch[mid] < g) lo = mid + 1; else hi = mid; }
      ptrv[g] = lo;
    }
  }
  __syncthreads();
  if (g < NG && ptrv[g] < ptrv[g + 1]) rootflag[ptrv[g]] = g + 1;
}

// ---------------- attention layer 1: 2 waves per dst (128 ch each), unroll-8 + rootcontrib tail
__global__ __launch_bounds__(512) void att1_kernel(
    const short* __restrict__ h1b, const float* __restrict__ asv, const float* __restrict__ adv,
    const int* __restrict__ offs, const int* __restrict__ csr, const float* __restrict__ b1,
    const int* __restrict__ rootflag, float* __restrict__ rootbuf, short* __restrict__ h1rb,
    const float* __restrict__ x, const float* __restrict__ W2, const int* __restrict__ ptrv,
    float* __restrict__ rc) {
  if (blockIdx.x >= A1B) {   // rootcontrib: rc[g][c] = relu(x[root_g]) @ W2[256:,c]
    int g = (blockIdx.x - A1B) * 4 + (threadIdx.x >> 7);
    int c = threadIdx.x & 127;
    if (g < NG) {
      int beg = ptrv[g], end = ptrv[g + 1];
      float s = 0.f;
      if (beg < end) {
        const float* xr = x + (long)beg * FIN;
        for (int k = 0; k < FIN; ++k) {
          float xv = xr[k]; xv = xv > 0.f ? xv : 0.f;
          s += xv * W2[(long)(HIDF + k) * OUTF + c];
        }
      }
      rc[g * 128 + c] = s;
    }
    return;
  }
  int wave = threadIdx.x >> 6;
  int d = blockIdx.x * 4 + (wave >> 1);
  int wh = wave & 1;                   // channel half: [wh*128, wh*128+128)
  int l = threadIdx.x & 63;
  int head = (wh << 1) | (l >> 5);     // (wh*128 + 2l) >> 6
  int beg = offs[d], end = offs[d + 1];
  float adh = sel4(((const float4*)adv)[d], head);
  float ash = sel4(((const float4*)asv)[d], head);
  float wSelf = __expf(lrelu(ash + adh));
  ushort2 sd = ((const ushort2*)h1b)[(long)d * 128 + wh * 64 + l];
  union { unsigned u; float f; } cu;
  cu.u = (unsigned)sd.x << 16; float ax = cu.f * wSelf;
  cu.u = (unsigned)sd.y << 16; float ay = cu.f * wSelf;
  float wsum = wSelf;
  for (int jj = beg; jj < end; jj += 8) {
    int s0 = (jj + 0 < end) ? csr[jj + 0] : d;
    int s1 = (jj + 1 < end) ? csr[jj + 1] : d;
    int s2 = (jj + 2 < end) ? csr[jj + 2] : d;
    int s3 = (jj + 3 < end) ? csr[jj + 3] : d;
    int s4 = (jj + 4 < end) ? csr[jj + 4] : d;
    int s5 = (jj + 5 < end) ? csr[jj + 5] : d;
    int s6 = (jj + 6 < end) ? csr[jj + 6] : d;
    int s7 = (jj + 7 < end) ? csr[jj + 7] : d;
    ushort2 r0 = ((const ushort2*)h1b)[(long)s0 * 128 + wh * 64 + l];
    ushort2 r1 = ((const ushort2*)h1b)[(long)s1 * 128 + wh * 64 + l];
    ushort2 r2 = ((const ushort2*)h1b)[(long)s2 * 128 + wh * 64 + l];
    ushort2 r3 = ((const ushort2*)h1b)[(long)s3 * 128 + wh * 64 + l];
    ushort2 r4 = ((const ushort2*)h1b)[(long)s4 * 128 + wh * 64 + l];
    ushort2 r5 = ((const ushort2*)h1b)[(long)s5 * 128 + wh * 64 + l];
    ushort2 r6 = ((const ushort2*)h1b)[(long)s6 * 128 + wh * 64 + l];
    ushort2 r7 = ((const ushort2*)h1b)[(long)s7 * 128 + wh * 64 + l];
    float4 A0 = ((const float4*)asv)[s0];
    float4 A1 = ((const float4*)asv)[s1];
    float4 A2 = ((const float4*)asv)[s2];
    float4 A3 = ((const float4*)asv)[s3];
    float4 A4 = ((const float4*)asv)[s4];
    float4 A5 = ((const float4*)asv)[s5];
    float4 A6 = ((const float4*)asv)[s6];
    float4 A7 = ((const float4*)asv)[s7];
    float w0 = (jj + 0 < end) ? __expf(lrelu(sel4(A0, head) + adh)) : 0.f;
    float w1 = (jj + 1 < end) ? __expf(lrelu(sel4(A1, head) + adh)) : 0.f;
    float w2 = (jj + 2 < end) ? __expf(lrelu(sel4(A2, head) + adh)) : 0.f;
    float w3 = (jj + 3 < end) ? __expf(lrelu(sel4(A3, head) + adh)) : 0.f;
    float w4 = (jj + 4 < end) ? __expf(lrelu(sel4(A4, head) + adh)) : 0.f;
    float w5 = (jj + 5 < end) ? __expf(lrelu(sel4(A5, head) + adh)) : 0.f;
    float w6 = (jj + 6 < end) ? __expf(lrelu(sel4(A6, head) + adh)) : 0.f;
    float w7 = (jj + 7 < end) ? __expf(lrelu(sel4(A7, head) + adh)) : 0.f;
    union { unsigned u; float f; } ux, uy;
    ux.u = (unsigned)r0.x << 16; uy.u = (unsigned)r0.y << 16; ax += ux.f * w0; ay += uy.f * w0; wsum += w0;
    ux.u = (unsigned)r1.x << 16; uy.u = (unsigned)r1.y << 16; ax += ux.f * w1; ay += uy.f * w1; wsum += w1;
    ux.u = (unsigned)r2.x << 16; uy.u = (unsigned)r2.y << 16; ax += ux.f * w2; ay += uy.f * w2; wsum += w2;
    ux.u = (unsigned)r3.x << 16; uy.u = (unsigned)r3.y << 16; ax += ux.f * w3; ay += uy.f * w3; wsum += w3;
    ux.u = (unsigned)r4.x << 16; uy.u = (unsigned)r4.y << 16; ax += ux.f * w4; ay += uy.f * w4; wsum += w4;
    ux.u = (unsigned)r5.x << 16; uy.u = (unsigned)r5.y << 16; ax += ux.f * w5; ay += uy.f * w5; wsum += w5;
    ux.u = (unsigned)r6.x << 16; uy.u = (unsigned)r6.y << 16; ax += ux.f * w6; ay += uy.f * w6; wsum += w6;
    ux.u = (unsigned)r7.x << 16; uy.u = (unsigned)r7.y << 16; ax += ux.f * w7; ay += uy.f * w7; wsum += w7;
  }
  float2 bv = ((const float2*)b1)[wh * 64 + l];
  float inv = 1.f / wsum;
  float ox = ax * inv + bv.x;
  float oy = ay * inv + bv.y;
  short2 ob;
  ob.x = f2bf(fmaxf(ox, 0.f));
  ob.y = f2bf(fmaxf(oy, 0.f));
  ((short2*)h1rb)[(long)d * 128 + wh * 64 + l] = ob;
  int rf = rootflag[d];
  if (rf > 0) {
    float2 rv; rv.x = ox; rv.y = oy;
    ((float2*)rootbuf)[(long)(rf - 1) * 128 + wh * 64 + l] = rv;
  }
}

// ---------------- attention layer 2: predicated unroll-8 + final relu, bf16 out
__global__ __launch_bounds__(256) void att2_kernel(
    const short* __restrict__ h2pb, const float* __restrict__ asv, const float* __restrict__ adv,
    const int* __restrict__ offs, const int* __restrict__ csr, const float* __restrict__ b2,
    short* __restrict__ h2b) {
  int d = blockIdx.x * 4 + (threadIdx.x >> 6);
  int l = threadIdx.x & 63;
  int head = l >> 4;                   // lane covers channels 2l,2l+1
  int beg = offs[d], end = offs[d + 1];
  float adh = sel4(((const float4*)adv)[d], head);
  float ash = sel4(((const float4*)asv)[d], head);
  float wSelf = __expf(lrelu(ash + adh));
  ushort2 hd = ((const ushort2*)h2pb)[(long)d * 64 + l];
  union { unsigned u; float f; } cv;
  cv.u = (unsigned)hd.x << 16; float accx = cv.f * wSelf;
  cv.u = (unsigned)hd.y << 16; float accy = cv.f * wSelf;
  float wsum = wSelf;
  for (int jj = beg; jj < end; jj += 8) {
    int s0 = (jj + 0 < end) ? csr[jj + 0] : d;
    int s1 = (jj + 1 < end) ? csr[jj + 1] : d;
    int s2 = (jj + 2 < end) ? csr[jj + 2] : d;
    int s3 = (jj + 3 < end) ? csr[jj + 3] : d;
    int s4 = (jj + 4 < end) ? csr[jj + 4] : d;
    int s5 = (jj + 5 < end) ? csr[jj + 5] : d;
    int s6 = (jj + 6 < end) ? csr[jj + 6] : d;
    int s7 = (jj + 7 < end) ? csr[jj + 7] : d;
    ushort2 r0 = ((const ushort2*)h2pb)[(long)s0 * 64 + l];
    ushort2 r1 = ((const ushort2*)h2pb)[(long)s1 * 64 + l];
    ushort2 r2 = ((const ushort2*)h2pb)[(long)s2 * 64 + l];
    ushort2 r3 = ((const ushort2*)h2pb)[(long)s3 * 64 + l];
    ushort2 r4 = ((const ushort2*)h2pb)[(long)s4 * 64 + l];
    ushort2 r5 = ((const ushort2*)h2pb)[(long)s5 * 64 + l];
    ushort2 r6 = ((const ushort2*)h2pb)[(long)s6 * 64 + l];
    ushort2 r7 = ((const ushort2*)h2pb)[(long)s7 * 64 + l];
    float4 A0 = ((const float4*)asv)[s0];
    float4 A1 = ((const float4*)asv)[s1];
    float4 A2 = ((const float4*)asv)[s2];
    float4 A3 = ((const float4*)asv)[s3];
    float4 A4 = ((const float4*)asv)[s4];
    float4 A5 = ((const float4*)asv)[s5];
    float4 A6 = ((const float4*)asv)[s6];
    float4 A7 = ((const float4*)asv)[s7];
    float w0 = (jj + 0 < end) ? __expf(lrelu(sel4(A0, head) + adh)) : 0.f;
    float w1 = (jj + 1 < end) ? __expf(lrelu(sel4(A1, head) + adh)) : 0.f;
    float w2 = (jj + 2 < end) ? __expf(lrelu(sel4(A2, head) + adh)) : 0.f;
    float w3 = (jj + 3 < end) ? __expf(lrelu(sel4(A3, head) + adh)) : 0.f;
    float w4 = (jj + 4 < end) ? __expf(lrelu(sel4(A4, head) + adh)) : 0.f;
    float w5 = (jj + 5 < end) ? __expf(lrelu(sel4(A5, head) + adh)) : 0.f;
    float w6 = (jj + 6 < end) ? __expf(lrelu(sel4(A6, head) + adh)) : 0.f;
    float w7 = (jj + 7 < end) ? __expf(lrelu(sel4(A7, head) + adh)) : 0.f;
    union { unsigned u; float f; } ux, uy;
    ux.u = (unsigned)r0.x << 16; uy.u = (unsigned)r0.y << 16; accx += ux.f * w0; accy += uy.f * w0; wsum += w0;
    ux.u = (unsigned)r1.x << 16; uy.u = (unsigned)r1.y << 16; accx += ux.f * w1; accy += uy.f * w1; wsum += w1;
    ux.u = (unsigned)r2.x << 16; uy.u = (unsigned)r2.y << 16; accx += ux.f * w2; accy += uy.f * w2; wsum += w2;
    ux.u = (unsigned)r3.x << 16; uy.u = (unsigned)r3.y << 16; accx += ux.f * w3; accy += uy.f * w3; wsum += w3;
    ux.u = (unsigned)r4.x << 16; uy.u = (unsigned)r4.y << 16; accx += ux.f * w4; accy += uy.f * w4; wsum += w4;
    ux.u = (unsigned)r5.x << 16; uy.u = (unsigned)r5.y << 16; accx += ux.f * w5; accy += uy.f * w5; wsum += w5;
    ux.u = (unsigned)r6.x << 16; uy.u = (unsigned)r6.y << 16; accx += ux.f * w6; accy += uy.f * w6; wsum += w6;
    ux.u = (unsigned)r7.x << 16; uy.u = (unsigned)r7.y << 16; accx += ux.f * w7; accy += uy.f * w7; wsum += w7;
  }
  float2 bv = ((const float2*)b2)[l];
  float inv = 1.f / wsum;
  float ox = accx * inv + bv.x, oy = accy * inv + bv.y;
  short2 o;
  o.x = f2bf(ox > 0.f ? ox : 0.f);
  o.y = f2bf(oy > 0.f ? oy : 0.f);
  ((short2*)h2b)[(long)d * 64 + l] = o;
}

// ---------------- pooling: out[g] = [mean(h2b rows), rootbuf[g]]
__global__ __launch_bounds__(1024) void pool_kernel(
    const short* __restrict__ h2b, const float* __restrict__ rootbuf,
    const int* __restrict__ ptrv, float* __restrict__ out) {
  int g = blockIdx.x;
  int t = threadIdx.x;
  int beg = ptrv[g], end = ptrv[g + 1];
  int cnt = end - beg;
  int cb = t & 31, seg = t >> 5;
  f32x4 acc = {0.f, 0.f, 0.f, 0.f};
  for (int n = beg + seg; n < end; n += 32)
    acc += b4f(((const ushort4*)h2b)[(long)n * 32 + cb]);
  __shared__ f32x4 sh[1024];
  sh[t] = acc; __syncthreads();
  for (int s = 512; s >= 32; s >>= 1) {
    if (t < s) sh[t] += sh[t + s];
    __syncthreads();
  }
  float inv = cnt > 0 ? 1.f / (float)cnt : 0.f;
  if (t < 32) {
    f32x4 v = sh[t] * inv;
    ((f32x4*)out)[(long)g * 96 + t] = v;
  } else if (t >= 64 && t < 128) {
    int i = t - 64;
    f32x4 rv = {0.f, 0.f, 0.f, 0.f};
    if (cnt > 0) rv = ((const f32x4*)rootbuf)[(long)g * 64 + i];
    ((f32x4*)out)[(long)g * 96 + 32 + i] = rv;
  }
}

extern "C" void kernel_launch(void* const* d_in, const int* in_sizes, int n_in,
                              void* d_out, int out_size, void* d_ws, size_t ws_size,
                              hipStream_t stream) {
  const float* x    = (const float*)d_in[0];
  const int*   srcv = (const int*)d_in[1];
  const int*   dstv = (const int*)d_in[2];
  const int*   batch= (const int*)d_in[3];
  const float* W1   = (const float*)d_in[4];
  const float* as1  = (const float*)d_in[5];
  const float* ad1  = (const float*)d_in[6];
  const float* b1   = (const float*)d_in[7];
  const float* W2   = (const float*)d_in[8];
  const float* as2  = (const float*)d_in[9];
  const float* ad2  = (const float*)d_in[10];
  const float* b2   = (const float*)d_in[11];
  float* out = (float*)d_out;

  char* ws = (char*)d_ws;
  auto alloc = [&](size_t bytes) -> char* {
    char* p = ws;
    ws += (bytes + 255) & ~(size_t)255;
    return p;
  };
  short* xb    = (short*)alloc((size_t)NN * FIN * 2);
  short* W1T   = (short*)alloc((size_t)HIDF * FIN * 2);
  short* W2T   = (short*)alloc((size_t)OUTF * HIDF * 2);
  short* h1b   = (short*)alloc((size_t)NN * HIDF * 2);
  short* h1rb  = (short*)alloc((size_t)NN * HIDF * 2);
  short* h2pb  = (short*)alloc((size_t)NN * OUTF * 2);
  short* h2b   = (short*)alloc((size_t)NN * OUTF * 2);
  float* as1v  = (float*)alloc((size_t)NN * 4 * 4);
  float* ad1v  = (float*)alloc((size_t)NN * 4 * 4);
  float* as2v  = (float*)alloc((size_t)NN * 4 * 4);
  float* ad2v  = (float*)alloc((size_t)NN * 4 * 4);
  int*   deg   = (int*)alloc((size_t)NN * 4);
  int*   offs  = (int*)alloc((size_t)(NN + 1) * 4);
  int*   cursor= (int*)alloc((size_t)NN * 4);
  int*   csr   = (int*)alloc((size_t)NE * 4);
  int*   bsum  = (int*)alloc(256 * 4);
  int*   bsumx = (int*)alloc(256 * 4);
  int*   bsum2 = (int*)alloc(16 * 4);
  int*   ptrv  = (int*)alloc((size_t)(NG + 1) * 4);
  int*   rootflag = (int*)alloc((size_t)NN * 4);
  float* rootbuf  = (float*)alloc((size_t)NG * HIDF * 4);
  float* rc    = (float*)alloc((size_t)NG * 128 * 4);

  zero_kernel<<<196, 256, 0, stream>>>(deg, rootflag);

  // prep: convert x, transpose weights, degree histogram (one launch)
  prep_kernel<<<4507, 256, 0, stream>>>(x, xb, W1, W1T, W2, W2T, dstv, deg);

  scan_block<<<196, 256, 0, stream>>>(deg, offs, bsum, NN);
  scan_block<<<1, 256, 0, stream>>>(bsum, bsumx, bsum2, 196);
  scan_add<<<196, 256, 0, stream>>>(offs, bsumx, cursor, NN, NE);
  scatter_ptr_kernel<<<1564, 256, 0, stream>>>(srcv, dstv, cursor, csr, batch, ptrv, rootflag);

  // GEMM1: h1b = bf16(xb @ W1), fused alphas (head = col>>6)
  gemm_kernel<false, 6><<<dim3(391, 2), 256, 0, stream>>>(
      xb, W1T, h1b, NN, FIN, HIDF, nullptr, nullptr, as1, ad1, as1v, ad1v);

  // att1: 2 waves per dst (+rootcontrib tail blocks)
  att1_kernel<<<A1B + 32, 512, 0, stream>>>(h1b, as1v, ad1v, offs, csr, b1,
                                            rootflag, rootbuf, h1rb, x, W2, ptrv, rc);

  // GEMM2: h2pb = bf16(relu(h1a) @ W2[:256] + rc[batch]), fused alphas (head = col>>5)
  gemm_kernel<true, 5><<<dim3(391, 1), 256, 0, stream>>>(
      h1rb, W2T, h2pb, NN, HIDF, OUTF, batch, rc, as2, ad2, as2v, ad2v);

  att2_kernel<<<12500, 256, 0, stream>>>(h2pb, as2v, ad2v, offs, csr, b2, h2b);

  pool_kernel<<<NG, 1024, 0, stream>>>(h2b, rootbuf, ptrv, out);
}

// Round 11
// 252.699 us; speedup vs baseline: 1.1577x; 1.1577x over previous
//
#include <hip/hip_runtime.h>

#define NN 50000
#define NE 400000
#define NG 128
#define FIN 768
#define HIDF 256
#define OUTF 128
#define RCB 64      // rootcontrib head blocks in att1 grid

typedef __attribute__((ext_vector_type(4))) float f32x4;
typedef __attribute__((ext_vector_type(8))) short bf16x8;

__device__ __forceinline__ short f2bf(float f) {
  union { float f; unsigned u; } v; v.f = f;
  unsigned r = v.u + 0x7FFFu + ((v.u >> 16) & 1u);   // RNE
  return (short)(r >> 16);
}
__device__ __forceinline__ float lrelu(float x) { return x > 0.f ? x : 0.2f * x; }
__device__ __forceinline__ f32x4 b4f(ushort4 v) {
  union { unsigned u; float f; } t;
  f32x4 r;
  t.u = (unsigned)v.x << 16; r[0] = t.f;
  t.u = (unsigned)v.y << 16; r[1] = t.f;
  t.u = (unsigned)v.z << 16; r[2] = t.f;
  t.u = (unsigned)v.w << 16; r[3] = t.f;
  return r;
}
__device__ __forceinline__ float sel4(float4 v, int head) {
  float t0 = (head & 1) ? v.y : v.x;
  float t1 = (head & 1) ? v.w : v.z;
  return (head & 2) ? t1 : t0;
}

__device__ __forceinline__ void gload16(const short* g, short* l) {
  __builtin_amdgcn_global_load_lds(
      (const __attribute__((address_space(1))) unsigned int*)g,
      (__attribute__((address_space(3))) unsigned int*)l, 16, 0, 0);
}

// ---------------- zero deg + rootflag
__global__ __launch_bounds__(256) void zero_kernel(int* __restrict__ deg,
                                                   int* __restrict__ rootflag) {
  int i = blockIdx.x * 256 + threadIdx.x;
  if (i < NN) { deg[i] = 0; rootflag[i] = 0; }
}

// ---------------- fused prep: x->bf16, W1^T->bf16, W2[:256]^T->bf16, deg histogram
__global__ __launch_bounds__(256) void prep_kernel(
    const float* __restrict__ x, short* __restrict__ xb,
    const float* __restrict__ W1, short* __restrict__ W1T,
    const float* __restrict__ W2, short* __restrict__ W2T,
    const int* __restrict__ dstv, int* __restrict__ deg) {
  int b = blockIdx.x;
  if (b < 2048) {                       // convert x (4.8M groups of 8)
    long n8 = (long)NN * FIN / 8;
    for (long i = (long)b * 256 + threadIdx.x; i < n8; i += 2048 * 256) {
      f32x4 v0 = ((const f32x4*)x)[i * 2];
      f32x4 v1 = ((const f32x4*)x)[i * 2 + 1];
      bf16x8 o;
      o[0] = f2bf(v0[0]); o[1] = f2bf(v0[1]); o[2] = f2bf(v0[2]); o[3] = f2bf(v0[3]);
      o[4] = f2bf(v1[0]); o[5] = f2bf(v1[1]); o[6] = f2bf(v1[2]); o[7] = f2bf(v1[3]);
      ((bf16x8*)xb)[i] = o;
    }
  } else if (b < 2048 + 768) {          // W1T[c*768+k] = W1[k*256+c]
    int idx = (b - 2048) * 256 + threadIdx.x;
    int c = idx / FIN, k = idx - c * FIN;
    W1T[idx] = f2bf(W1[(long)k * HIDF + c]);
  } else if (b < 2048 + 768 + 128) {    // W2T[c*256+k] = W2[k*128+c], k<256
    int idx = (b - 2816) * 256 + threadIdx.x;
    int c = idx / HIDF, k = idx - c * HIDF;
    W2T[idx] = f2bf(W2[(long)k * OUTF + c]);
  } else {                              // deg histogram
    int e = (b - 2944) * 256 + threadIdx.x;
    if (e < NE) atomicAdd(&deg[dstv[e]], 1);
  }
}

// ---------------- MFMA GEMM, async global_load_lds staging, fused alphas, bf16 C
template<bool ADD_RC, int HEAD_SHIFT>
__global__ __launch_bounds__(256, 2) void gemm_kernel(
    const short* __restrict__ A, const short* __restrict__ Bt,
    short* __restrict__ C, int M, int K, int NC,
    const int* __restrict__ batch, const float* __restrict__ rc,
    const float* __restrict__ a_s, const float* __restrict__ a_d,
    float* __restrict__ as_out, float* __restrict__ ad_out)
{
  __shared__ short As[2][128 * 64];
  __shared__ short Bs[2][128 * 64];
  const int tid = threadIdx.x;
  const int l = tid & 63;
  const int w = tid >> 6;
  const int wm = w >> 1, wn = w & 1;
  const int bm = blockIdx.x, bn = blockIdx.y;
  const int nsteps = K >> 6;
  f32x4 acc[4][4] = {};

  auto issue = [&](int buf, int kt) {
    #pragma unroll
    for (int j = 0; j < 4; ++j) {
      int c = w * 4 + j;
      int q = c * 64 + l;
      int row = q >> 3, js = q & 7;
      int kg = js ^ (row & 7);            // source-address pre-swizzle
      long grow = (long)bm * 128 + row; if (grow >= M) grow = M - 1;
      gload16(A + grow * (long)K + kt * 64 + kg * 8, &As[buf][c * 512]);
    }
    #pragma unroll
    for (int j = 0; j < 4; ++j) {
      int c = w * 4 + j;
      int q = c * 64 + l;
      int row = q >> 3, js = q & 7;
      int kg = js ^ (row & 7);
      gload16(Bt + (long)(bn * 128 + row) * K + kt * 64 + kg * 8, &Bs[buf][c * 512]);
    }
  };

  issue(0, 0);
  if (nsteps > 1) {
    issue(1, 1);
    asm volatile("s_waitcnt vmcnt(8)" ::: "memory");
  } else {
    asm volatile("s_waitcnt vmcnt(0)" ::: "memory");
  }
  __builtin_amdgcn_s_barrier();

  for (int kt = 0; kt < nsteps; ++kt) {
    const int buf = kt & 1;
    const char* Ab = (const char*)&As[buf][0];
    const char* Bb = (const char*)&Bs[buf][0];
    #pragma unroll
    for (int ks = 0; ks < 2; ++ks) {
      bf16x8 af[4], bfr[4];
      #pragma unroll
      for (int mf = 0; mf < 4; ++mf) {
        int row = wm * 64 + mf * 16 + (l & 15);
        int off = (row * 128 + ks * 64 + (l >> 4) * 16) ^ ((row & 7) << 4);
        af[mf] = *(const bf16x8*)(Ab + off);
      }
      #pragma unroll
      for (int nf = 0; nf < 4; ++nf) {
        int row = wn * 64 + nf * 16 + (l & 15);
        int off = (row * 128 + ks * 64 + (l >> 4) * 16) ^ ((row & 7) << 4);
        bfr[nf] = *(const bf16x8*)(Bb + off);
      }
      #pragma unroll
      for (int mf = 0; mf < 4; ++mf)
        #pragma unroll
        for (int nf = 0; nf < 4; ++nf)
          acc[mf][nf] = __builtin_amdgcn_mfma_f32_16x16x32_bf16(af[mf], bfr[nf], acc[mf][nf], 0, 0, 0);
    }
    if (kt + 1 < nsteps) {
      asm volatile("s_waitcnt lgkmcnt(0)" ::: "memory");
      __builtin_amdgcn_s_barrier();
      if (kt + 2 < nsteps) {
        issue(buf, kt + 2);
        asm volatile("s_waitcnt vmcnt(8)" ::: "memory");
      } else {
        asm volatile("s_waitcnt vmcnt(0)" ::: "memory");
      }
      __builtin_amdgcn_s_barrier();
    }
  }

  // ---- epilogue: bf16 C store + fused per-head alpha dot products
  float asr[4], adr[4];
  #pragma unroll
  for (int nf = 0; nf < 4; ++nf) {
    int col = bn * 128 + wn * 64 + nf * 16 + (l & 15);
    asr[nf] = a_s[col]; adr[nf] = a_d[col];
  }
  #pragma unroll
  for (int mf = 0; mf < 4; ++mf) {
    #pragma unroll
    for (int r = 0; r < 4; ++r) {
      long grow = (long)bm * 128 + wm * 64 + mf * 16 + (l >> 4) * 4 + r;
      bool valid = grow < M;
      long rcb = 0;
      if (ADD_RC && valid) rcb = (long)batch[grow] * 128;
      float ps0 = 0, pd0 = 0, ps1 = 0, pd1 = 0;
      #pragma unroll
      for (int nf = 0; nf < 4; ++nf) {
        int col = bn * 128 + wn * 64 + nf * 16 + (l & 15);
        float v = acc[mf][nf][r];
        if (ADD_RC && valid) v += rc[rcb + col];
        if (valid) C[grow * (long)NC + col] = f2bf(v);
        float vs = v * asr[nf], vd = v * adr[nf];
        if (HEAD_SHIFT == 6 || nf < 2) { ps0 += vs; pd0 += vd; }
        else { ps1 += vs; pd1 += vd; }
      }
      #pragma unroll
      for (int off = 1; off < 16; off <<= 1) {
        ps0 += __shfl_xor(ps0, off); pd0 += __shfl_xor(pd0, off);
        if (HEAD_SHIFT == 5) { ps1 += __shfl_xor(ps1, off); pd1 += __shfl_xor(pd1, off); }
      }
      if (valid && (l & 15) == 0) {
        if (HEAD_SHIFT == 6) {
          int h0 = bn * 2 + wn;
          as_out[grow * 4 + h0] = ps0; ad_out[grow * 4 + h0] = pd0;
        } else {
          int h0 = wn * 2;
          as_out[grow * 4 + h0] = ps0;     ad_out[grow * 4 + h0] = pd0;
          as_out[grow * 4 + h0 + 1] = ps1; ad_out[grow * 4 + h0 + 1] = pd1;
        }
      }
    }
  }
}

// ---------------- CSR scan chain
__global__ void scan_block(const int* __restrict__ in, int* __restrict__ out,
                           int* __restrict__ bsum, int n) {
  __shared__ int sh[256];
  int i = blockIdx.x * 256 + threadIdx.x;
  int v = (i < n) ? in[i] : 0;
  int sum = v;
  sh[threadIdx.x] = v; __syncthreads();
  #pragma unroll
  for (int off = 1; off < 256; off <<= 1) {
    int t = (threadIdx.x >= off) ? sh[threadIdx.x - off] : 0;
    __syncthreads();
    sum += t;
    sh[threadIdx.x] = sum;
    __syncthreads();
  }
  if (i < n) out[i] = sum - v;     // exclusive
  if (threadIdx.x == 255) bsum[blockIdx.x] = sum;
}
__global__ void scan_add(int* __restrict__ offs, const int* __restrict__ bsumx,
                         int* __restrict__ cursor, int n, int total) {
  int i = blockIdx.x * 256 + threadIdx.x;
  if (i < n) { int v = offs[i] + bsumx[i >> 8]; offs[i] = v; cursor[i] = v; }
  if (i == n) offs[n] = total;
}
// scatter + graph-root pointers fused
__global__ void scatter_ptr_kernel(const int* __restrict__ src, const int* __restrict__ dst,
                                   int* __restrict__ cursor, int* __restrict__ csr,
                                   const int* __restrict__ batch, int* __restrict__ ptrv,
                                   int* __restrict__ rootflag) {
  if (blockIdx.x < 1563) {
    int e = blockIdx.x * 256 + threadIdx.x;
    if (e < NE) { int d = dst[e]; int p = atomicAdd(&cursor[d], 1); csr[p] = src[e]; }
    return;
  }
  int g = threadIdx.x;
  if (g <= NG) {
    if (g == NG) ptrv[NG] = NN;
    else {
      int lo = 0, hi = NN;
      while (lo < hi) { int mid = (lo + hi) >> 1; if (batch[mid] < g) lo = mid + 1; else hi = mid; }
      ptrv[g] = lo;
    }
  }
  __syncthreads();
  if (g < NG && ptrv[g] < ptrv[g + 1]) rootflag[ptrv[g]] = g + 1;
}

// ---------------- attention layer 1: rootcontrib HEAD blocks + 1 wave/dst unroll-8
__global__ __launch_bounds__(256) void att1_kernel(
    const short* __restrict__ h1b, const float* __restrict__ asv, const float* __restrict__ adv,
    const int* __restrict__ offs, const int* __restrict__ csr, const float* __restrict__ b1,
    const int* __restrict__ rootflag, float* __restrict__ rootbuf, short* __restrict__ h1rb,
    const float* __restrict__ x, const float* __restrict__ W2, const int* __restrict__ ptrv,
    float* __restrict__ rc) {
  if (blockIdx.x < RCB) {    // rootcontrib FIRST (overlaps the att sweep)
    int g = blockIdx.x * 2 + (threadIdx.x >> 7);
    int c = threadIdx.x & 127;
    if (g < NG) {
      int beg = ptrv[g], end = ptrv[g + 1];
      float s = 0.f;
      if (beg < end) {
        const float* xr = x + (long)beg * FIN;
        for (int k = 0; k < FIN; ++k) {
          float xv = xr[k]; xv = xv > 0.f ? xv : 0.f;
          s += xv * W2[(long)(HIDF + k) * OUTF + c];
        }
      }
      rc[g * 128 + c] = s;
    }
    return;
  }
  int d = (blockIdx.x - RCB) * 4 + (threadIdx.x >> 6);
  int l = threadIdx.x & 63;
  int head = l >> 4;                   // lane covers channels 4l..4l+3
  int beg = offs[d], end = offs[d + 1];
  float adh = sel4(((const float4*)adv)[d], head);
  float ash = sel4(((const float4*)asv)[d], head);
  float wSelf = __expf(lrelu(ash + adh));
  f32x4 acc = b4f(((const ushort4*)h1b)[(long)d * 64 + l]) * wSelf;
  float wsum = wSelf;
  for (int jj = beg; jj < end; jj += 8) {
    int s0 = (jj + 0 < end) ? csr[jj + 0] : d;
    int s1 = (jj + 1 < end) ? csr[jj + 1] : d;
    int s2 = (jj + 2 < end) ? csr[jj + 2] : d;
    int s3 = (jj + 3 < end) ? csr[jj + 3] : d;
    int s4 = (jj + 4 < end) ? csr[jj + 4] : d;
    int s5 = (jj + 5 < end) ? csr[jj + 5] : d;
    int s6 = (jj + 6 < end) ? csr[jj + 6] : d;
    int s7 = (jj + 7 < end) ? csr[jj + 7] : d;
    // issue all row + alpha gathers before consuming (16 VMEM in flight)
    ushort4 r0 = ((const ushort4*)h1b)[(long)s0 * 64 + l];
    ushort4 r1 = ((const ushort4*)h1b)[(long)s1 * 64 + l];
    ushort4 r2 = ((const ushort4*)h1b)[(long)s2 * 64 + l];
    ushort4 r3 = ((const ushort4*)h1b)[(long)s3 * 64 + l];
    ushort4 r4 = ((const ushort4*)h1b)[(long)s4 * 64 + l];
    ushort4 r5 = ((const ushort4*)h1b)[(long)s5 * 64 + l];
    ushort4 r6 = ((const ushort4*)h1b)[(long)s6 * 64 + l];
    ushort4 r7 = ((const ushort4*)h1b)[(long)s7 * 64 + l];
    float4 A0 = ((const float4*)asv)[s0];
    float4 A1 = ((const float4*)asv)[s1];
    float4 A2 = ((const float4*)asv)[s2];
    float4 A3 = ((const float4*)asv)[s3];
    float4 A4 = ((const float4*)asv)[s4];
    float4 A5 = ((const float4*)asv)[s5];
    float4 A6 = ((const float4*)asv)[s6];
    float4 A7 = ((const float4*)asv)[s7];
    float w0 = (jj + 0 < end) ? __expf(lrelu(sel4(A0, head) + adh)) : 0.f;
    float w1 = (jj + 1 < end) ? __expf(lrelu(sel4(A1, head) + adh)) : 0.f;
    float w2 = (jj + 2 < end) ? __expf(lrelu(sel4(A2, head) + adh)) : 0.f;
    float w3 = (jj + 3 < end) ? __expf(lrelu(sel4(A3, head) + adh)) : 0.f;
    float w4 = (jj + 4 < end) ? __expf(lrelu(sel4(A4, head) + adh)) : 0.f;
    float w5 = (jj + 5 < end) ? __expf(lrelu(sel4(A5, head) + adh)) : 0.f;
    float w6 = (jj + 6 < end) ? __expf(lrelu(sel4(A6, head) + adh)) : 0.f;
    float w7 = (jj + 7 < end) ? __expf(lrelu(sel4(A7, head) + adh)) : 0.f;
    acc += b4f(r0) * w0; wsum += w0;
    acc += b4f(r1) * w1; wsum += w1;
    acc += b4f(r2) * w2; wsum += w2;
    acc += b4f(r3) * w3; wsum += w3;
    acc += b4f(r4) * w4; wsum += w4;
    acc += b4f(r5) * w5; wsum += w5;
    acc += b4f(r6) * w6; wsum += w6;
    acc += b4f(r7) * w7; wsum += w7;
  }
  f32x4 bb = ((const f32x4*)b1)[l];
  f32x4 o = acc * (1.f / wsum) + bb;
  short4 ob;
  ob.x = f2bf(fmaxf(o[0], 0.f)); ob.y = f2bf(fmaxf(o[1], 0.f));
  ob.z = f2bf(fmaxf(o[2], 0.f)); ob.w = f2bf(fmaxf(o[3], 0.f));
  ((short4*)h1rb)[(long)d * 64 + l] = ob;
  int rf = rootflag[d];
  if (rf > 0) ((f32x4*)rootbuf)[(long)(rf - 1) * 64 + l] = o;
}

// ---------------- attention layer 2: predicated unroll-8 + final relu, bf16 out
__global__ __launch_bounds__(256) void att2_kernel(
    const short* __restrict__ h2pb, const float* __restrict__ asv, const float* __restrict__ adv,
    const int* __restrict__ offs, const int* __restrict__ csr, const float* __restrict__ b2,
    short* __restrict__ h2b) {
  int d = blockIdx.x * 4 + (threadIdx.x >> 6);
  int l = threadIdx.x & 63;
  int head = l >> 4;                   // lane covers channels 2l,2l+1
  int beg = offs[d], end = offs[d + 1];
  float adh = sel4(((const float4*)adv)[d], head);
  float ash = sel4(((const float4*)asv)[d], head);
  float wSelf = __expf(lrelu(ash + adh));
  ushort2 hd = ((const ushort2*)h2pb)[(long)d * 64 + l];
  union { unsigned u; float f; } cv;
  cv.u = (unsigned)hd.x << 16; float accx = cv.f * wSelf;
  cv.u = (unsigned)hd.y << 16; float accy = cv.f * wSelf;
  float wsum = wSelf;
  for (int jj = beg; jj < end; jj += 8) {
    int s0 = (jj + 0 < end) ? csr[jj + 0] : d;
    int s1 = (jj + 1 < end) ? csr[jj + 1] : d;
    int s2 = (jj + 2 < end) ? csr[jj + 2] : d;
    int s3 = (jj + 3 < end) ? csr[jj + 3] : d;
    int s4 = (jj + 4 < end) ? csr[jj + 4] : d;
    int s5 = (jj + 5 < end) ? csr[jj + 5] : d;
    int s6 = (jj + 6 < end) ? csr[jj + 6] : d;
    int s7 = (jj + 7 < end) ? csr[jj + 7] : d;
    ushort2 r0 = ((const ushort2*)h2pb)[(long)s0 * 64 + l];
    ushort2 r1 = ((const ushort2*)h2pb)[(long)s1 * 64 + l];
    ushort2 r2 = ((const ushort2*)h2pb)[(long)s2 * 64 + l];
    ushort2 r3 = ((const ushort2*)h2pb)[(long)s3 * 64 + l];
    ushort2 r4 = ((const ushort2*)h2pb)[(long)s4 * 64 + l];
    ushort2 r5 = ((const ushort2*)h2pb)[(long)s5 * 64 + l];
    ushort2 r6 = ((const ushort2*)h2pb)[(long)s6 * 64 + l];
    ushort2 r7 = ((const ushort2*)h2pb)[(long)s7 * 64 + l];
    float4 A0 = ((const float4*)asv)[s0];
    float4 A1 = ((const float4*)asv)[s1];
    float4 A2 = ((const float4*)asv)[s2];
    float4 A3 = ((const float4*)asv)[s3];
    float4 A4 = ((const float4*)asv)[s4];
    float4 A5 = ((const float4*)asv)[s5];
    float4 A6 = ((const float4*)asv)[s6];
    float4 A7 = ((const float4*)asv)[s7];
    float w0 = (jj + 0 < end) ? __expf(lrelu(sel4(A0, head) + adh)) : 0.f;
    float w1 = (jj + 1 < end) ? __expf(lrelu(sel4(A1, head) + adh)) : 0.f;
    float w2 = (jj + 2 < end) ? __expf(lrelu(sel4(A2, head) + adh)) : 0.f;
    float w3 = (jj + 3 < end) ? __expf(lrelu(sel4(A3, head) + adh)) : 0.f;
    float w4 = (jj + 4 < end) ? __expf(lrelu(sel4(A4, head) + adh)) : 0.f;
    float w5 = (jj + 5 < end) ? __expf(lrelu(sel4(A5, head) + adh)) : 0.f;
    float w6 = (jj + 6 < end) ? __expf(lrelu(sel4(A6, head) + adh)) : 0.f;
    float w7 = (jj + 7 < end) ? __expf(lrelu(sel4(A7, head) + adh)) : 0.f;
    union { unsigned u; float f; } ux, uy;
    ux.u = (unsigned)r0.x << 16; uy.u = (unsigned)r0.y << 16; accx += ux.f * w0; accy += uy.f * w0; wsum += w0;
    ux.u = (unsigned)r1.x << 16; uy.u = (unsigned)r1.y << 16; accx += ux.f * w1; accy += uy.f * w1; wsum += w1;
    ux.u = (unsigned)r2.x << 16; uy.u = (unsigned)r2.y << 16; accx += ux.f * w2; accy += uy.f * w2; wsum += w2;
    ux.u = (unsigned)r3.x << 16; uy.u = (unsigned)r3.y << 16; accx += ux.f * w3; accy += uy.f * w3; wsum += w3;
    ux.u = (unsigned)r4.x << 16; uy.u = (unsigned)r4.y << 16; accx += ux.f * w4; accy += uy.f * w4; wsum += w4;
    ux.u = (unsigned)r5.x << 16; uy.u = (unsigned)r5.y << 16; accx += ux.f * w5; accy += uy.f * w5; wsum += w5;
    ux.u = (unsigned)r6.x << 16; uy.u = (unsigned)r6.y << 16; accx += ux.f * w6; accy += uy.f * w6; wsum += w6;
    ux.u = (unsigned)r7.x << 16; uy.u = (unsigned)r7.y << 16; accx += ux.f * w7; accy += uy.f * w7; wsum += w7;
  }
  float2 bv = ((const float2*)b2)[l];
  float inv = 1.f / wsum;
  float ox = accx * inv + bv.x, oy = accy * inv + bv.y;
  short2 o;
  o.x = f2bf(ox > 0.f ? ox : 0.f);
  o.y = f2bf(oy > 0.f ? oy : 0.f);
  ((short2*)h2b)[(long)d * 64 + l] = o;
}

// ---------------- pooling: out[g] = [mean(h2b rows), rootbuf[g]]
__global__ __launch_bounds__(1024) void pool_kernel(
    const short* __restrict__ h2b, const float* __restrict__ rootbuf,
    const int* __restrict__ ptrv, float* __restrict__ out) {
  int g = blockIdx.x;
  int t = threadIdx.x;
  int beg = ptrv[g], end = ptrv[g + 1];
  int cnt = end - beg;
  int cb = t & 31, seg = t >> 5;
  f32x4 acc = {0.f, 0.f, 0.f, 0.f};
  for (int n = beg + seg; n < end; n += 32)
    acc += b4f(((const ushort4*)h2b)[(long)n * 32 + cb]);
  __shared__ f32x4 sh[1024];
  sh[t] = acc; __syncthreads();
  for (int s = 512; s >= 32; s >>= 1) {
    if (t < s) sh[t] += sh[t + s];
    __syncthreads();
  }
  float inv = cnt > 0 ? 1.f / (float)cnt : 0.f;
  if (t < 32) {
    f32x4 v = sh[t] * inv;
    ((f32x4*)out)[(long)g * 96 + t] = v;
  } else if (t >= 64 && t < 128) {
    int i = t - 64;
    f32x4 rv = {0.f, 0.f, 0.f, 0.f};
    if (cnt > 0) rv = ((const f32x4*)rootbuf)[(long)g * 64 + i];
    ((f32x4*)out)[(long)g * 96 + 32 + i] = rv;
  }
}

extern "C" void kernel_launch(void* const* d_in, const int* in_sizes, int n_in,
                              void* d_out, int out_size, void* d_ws, size_t ws_size,
                              hipStream_t stream) {
  const float* x    = (const float*)d_in[0];
  const int*   srcv = (const int*)d_in[1];
  const int*   dstv = (const int*)d_in[2];
  const int*   batch= (const int*)d_in[3];
  const float* W1   = (const float*)d_in[4];
  const float* as1  = (const float*)d_in[5];
  const float* ad1  = (const float*)d_in[6];
  const float* b1   = (const float*)d_in[7];
  const float* W2   = (const float*)d_in[8];
  const float* as2  = (const float*)d_in[9];
  const float* ad2  = (const float*)d_in[10];
  const float* b2   = (const float*)d_in[11];
  float* out = (float*)d_out;

  char* ws = (char*)d_ws;
  auto alloc = [&](size_t bytes) -> char* {
    char* p = ws;
    ws += (bytes + 255) & ~(size_t)255;
    return p;
  };
  short* xb    = (short*)alloc((size_t)NN * FIN * 2);
  short* W1T   = (short*)alloc((size_t)HIDF * FIN * 2);
  short* W2T   = (short*)alloc((size_t)OUTF * HIDF * 2);
  short* h1b   = (short*)alloc((size_t)NN * HIDF * 2);
  short* h1rb  = (short*)alloc((size_t)NN * HIDF * 2);
  short* h2pb  = (short*)alloc((size_t)NN * OUTF * 2);
  short* h2b   = (short*)alloc((size_t)NN * OUTF * 2);
  float* as1v  = (float*)alloc((size_t)NN * 4 * 4);
  float* ad1v  = (float*)alloc((size_t)NN * 4 * 4);
  float* as2v  = (float*)alloc((size_t)NN * 4 * 4);
  float* ad2v  = (float*)alloc((size_t)NN * 4 * 4);
  int*   deg   = (int*)alloc((size_t)NN * 4);
  int*   offs  = (int*)alloc((size_t)(NN + 1) * 4);
  int*   cursor= (int*)alloc((size_t)NN * 4);
  int*   csr   = (int*)alloc((size_t)NE * 4);
  int*   bsum  = (int*)alloc(256 * 4);
  int*   bsumx = (int*)alloc(256 * 4);
  int*   bsum2 = (int*)alloc(16 * 4);
  int*   ptrv  = (int*)alloc((size_t)(NG + 1) * 4);
  int*   rootflag = (int*)alloc((size_t)NN * 4);
  float* rootbuf  = (float*)alloc((size_t)NG * HIDF * 4);
  float* rc    = (float*)alloc((size_t)NG * 128 * 4);

  zero_kernel<<<196, 256, 0, stream>>>(deg, rootflag);

  // prep: convert x, transpose weights, degree histogram (one launch)
  prep_kernel<<<4507, 256, 0, stream>>>(x, xb, W1, W1T, W2, W2T, dstv, deg);

  scan_block<<<196, 256, 0, stream>>>(deg, offs, bsum, NN);
  scan_block<<<1, 256, 0, stream>>>(bsum, bsumx, bsum2, 196);
  scan_add<<<196, 256, 0, stream>>>(offs, bsumx, cursor, NN, NE);
  scatter_ptr_kernel<<<1564, 256, 0, stream>>>(srcv, dstv, cursor, csr, batch, ptrv, rootflag);

  // GEMM1: h1b = bf16(xb @ W1), fused alphas (head = col>>6)
  gemm_kernel<false, 6><<<dim3(391, 2), 256, 0, stream>>>(
      xb, W1T, h1b, NN, FIN, HIDF, nullptr, nullptr, as1, ad1, as1v, ad1v);

  // att1 (rootcontrib head blocks + 12500 att blocks)
  att1_kernel<<<RCB + 12500, 256, 0, stream>>>(h1b, as1v, ad1v, offs, csr, b1,
                                               rootflag, rootbuf, h1rb, x, W2, ptrv, rc);

  // GEMM2: h2pb = bf16(relu(h1a) @ W2[:256] + rc[batch]), fused alphas (head = col>>5)
  gemm_kernel<true, 5><<<dim3(391, 1), 256, 0, stream>>>(
      h1rb, W2T, h2pb, NN, HIDF, OUTF, batch, rc, as2, ad2, as2v, ad2v);

  att2_kernel<<<12500, 256, 0, stream>>>(h2pb, as2v, ad2v, offs, csr, b2, h2b);

  pool_kernel<<<NG, 1024, 0, stream>>>(h2b, rootbuf, ptrv, out);
}